// Round 15
// baseline (112.588 us; speedup 1.0000x reference)
//
#include <hip/hip_runtime.h>

#define NSEQ 2048
#define DH 64
// SCALE * log2(e): softmax tracked in log2 domain (exp -> bare v_exp_f32)
#define QSCALE (0.125f * 1.44269504088896340736f)
#define DEFER_THR 11.5415603f   // 8 * log2(e)
#define QBLK 256
#define KVBLK 128
#define NTILE (NSEQ / KVBLK)    // 16
#define KP 72   // Kt row pitch (144B): conflict-minimal b128 reads, 2-way writes

typedef _Float16 f16x8 __attribute__((ext_vector_type(8)));
typedef _Float16 f16x4 __attribute__((ext_vector_type(4)));
typedef __fp16 fp16x2 __attribute__((ext_vector_type(2)));
typedef float f32x4 __attribute__((ext_vector_type(4)));
typedef unsigned u32x2 __attribute__((ext_vector_type(2)));

// RAW v_exp_f32 (2^x; flush-to-zero for x<-126 is semantically fine here).
#if defined(__has_builtin) && __has_builtin(__builtin_amdgcn_exp2f)
#define EXP2R(x) __builtin_amdgcn_exp2f(x)
#else
static __device__ __forceinline__ float EXP2R(float x) {
    float r; asm("v_exp_f32 %0, %1" : "=v"(r) : "v"(x)); return r;
}
#endif

// Cross-group (lane^32 then lane^16) reduce via permlane swaps: VALU-only,
// replaces ds_bpermute-based __shfl_xor on the softmax critical path.
static __device__ __forceinline__ float gmax4(float x) {
    unsigned xu = __float_as_uint(x);
    u32x2 p = __builtin_amdgcn_permlane32_swap(xu, xu, false, false);
    float y = fmaxf(__uint_as_float(p[0]), __uint_as_float(p[1]));
    unsigned yu = __float_as_uint(y);
    u32x2 q = __builtin_amdgcn_permlane16_swap(yu, yu, false, false);
    return fmaxf(__uint_as_float(q[0]), __uint_as_float(q[1]));
}
static __device__ __forceinline__ float gsum4(float x) {
    unsigned xu = __float_as_uint(x);
    u32x2 p = __builtin_amdgcn_permlane32_swap(xu, xu, false, false);
    float y = __uint_as_float(p[0]) + __uint_as_float(p[1]);
    unsigned yu = __float_as_uint(y);
    u32x2 q = __builtin_amdgcn_permlane16_swap(yu, yu, false, false);
    return __uint_as_float(q[0]) + __uint_as_float(q[1]);
}

union TrP { f16x4 h[2]; f16x8 v8; };

// tr-read: per-lane addr = 128B-aligned subtile base + l15*8
#define TRRD(dst, bb, lit) \
    asm volatile("ds_read_b64_tr_b16 %0, %1 offset:" lit : "=v"(dst) : "v"(bb))

// float4 -> f16x4 via packed cvt
#define CVT4(dst, f4) do { \
        union { fp16x2 f2[2]; f16x4 h4; } _u; \
        _u.f2[0] = __builtin_amdgcn_cvt_pkrtz((f4).x, (f4).y); \
        _u.f2[1] = __builtin_amdgcn_cvt_pkrtz((f4).z, (f4).w); \
        (dst) = _u.h4; } while (0)

__global__ __launch_bounds__(512, 4)
void fa_fwd(const float* __restrict__ Qg, const float* __restrict__ Kg,
            const float* __restrict__ Vg, float* __restrict__ Og)
{
    __shared__ _Float16 Kt[2][KVBLK * KP];   // 36864 B
    __shared__ _Float16 Vt[2][KVBLK * DH];   // 32768 B, subtiled [kv/4][d/16][4][16]

    const int tid  = threadIdx.x;
    const int lane = tid & 63;
    const int wv   = tid >> 6;
    const int l15  = lane & 15;
    const int g    = lane >> 4;

    // XCD-aware swizzle: 512 blocks / 8 XCDs
    const int id  = blockIdx.x;
    const int w   = (id & 7) * 64 + (id >> 3);
    const int bh  = w >> 3;
    const int qb0 = (w & 7) * QBLK;
    const size_t base = (size_t)bh * NSEQ * DH;

    f16x8 qf[2][2];
#pragma unroll
    for (int u = 0; u < 2; ++u) {
        const float* qp = Qg + base + (size_t)(qb0 + wv * 32 + u * 16 + l15) * DH;
#pragma unroll
        for (int ks = 0; ks < 2; ++ks)
#pragma unroll
            for (int j = 0; j < 8; ++j)
                qf[u][ks][j] = (_Float16)(qp[32 * ks + 8 * g + j] * QSCALE);
    }

    f32x4 acc[2][4];
#pragma unroll
    for (int u = 0; u < 2; ++u)
#pragma unroll
        for (int nt = 0; nt < 4; ++nt)
            acc[u][nt] = (f32x4){0.f, 0.f, 0.f, 0.f};
    // m starts at 0 (finite) so -m seeds the MFMA C operand; defer-max
    // handles growth (fires only when excess > THR).
    float m_run[2] = {0.f, 0.f};
    float l_run[2] = {0.f, 0.f};   // per-lane PARTIAL; reduced in epilogue

    // staging map (conflict-free Vt writes), covering 128 kv rows
    const int grp = tid >> 4;
    const int kb4 = grp >> 1;
    const int dhh = (grp & 1) * 32;
    const int kva = kb4 * 4 + (l15 >> 2);
    const int d0a = dhh + (l15 & 3) * 4;
    const int d0b = d0a + 16;
    const float* Kbp = Kg + base;
    const float* Vbp = Vg + base;
    const int offA = kva * DH + d0a;
    const int offB = kva * DH + d0b;
    const int offC = offA + 64 * DH;
    const int offD = offB + 64 * DH;
    const int vta = ((kva >> 2) * 4 + (d0a >> 4)) * 64 + (kva & 3) * 16 + (d0a & 15);
    const int vtb = ((kva >> 2) * 4 + (d0b >> 4)) * 64 + (kva & 3) * 16 + (d0b & 15);
    const int vtc = vta + 4096;
    const int vtd = vtb + 4096;
    const int kta = kva * KP + d0a;
    const int ktb = kva * KP + d0b;
    const int ktc = kta + 64 * KP;
    const int ktd = ktb + 64 * KP;

    // initial full stage (loads+cvt+writes, short-lived regs)
    {
        float4 f0 = *(const float4*)(Kbp + offA);
        float4 f1 = *(const float4*)(Kbp + offB);
        float4 f2 = *(const float4*)(Kbp + offC);
        float4 f3 = *(const float4*)(Kbp + offD);
        float4 f4v = *(const float4*)(Vbp + offA);
        float4 f5 = *(const float4*)(Vbp + offB);
        float4 f6 = *(const float4*)(Vbp + offC);
        float4 f7 = *(const float4*)(Vbp + offD);
        f16x4 h;
        CVT4(h, f0); *(f16x4*)&Kt[0][kta] = h;
        CVT4(h, f1); *(f16x4*)&Kt[0][ktb] = h;
        CVT4(h, f2); *(f16x4*)&Kt[0][ktc] = h;
        CVT4(h, f3); *(f16x4*)&Kt[0][ktd] = h;
        CVT4(h, f4v); *(f16x4*)&Vt[0][vta] = h;
        CVT4(h, f5); *(f16x4*)&Vt[0][vtb] = h;
        CVT4(h, f6); *(f16x4*)&Vt[0][vtc] = h;
        CVT4(h, f7); *(f16x4*)&Vt[0][vtd] = h;
    }
    __syncthreads();

    const float* kpre = Kbp + KVBLK * DH;
    const float* vpre = Vbp + KVBLK * DH;

    const unsigned vtrb = (unsigned)(size_t)(&Vt[0][0]) + (unsigned)(g * 1024 + l15 * 8);
    const fp16x2 ones2 = {(__fp16)1.0f, (__fp16)1.0f};

    float4 kp0, kp1, kp2, kp3;   // K prefetch (issued mid-tile, used at stage)

    for (int t = 0; t < NTILE; ++t) {
        const int c = t & 1;
        const unsigned vbuf = vtrb + (unsigned)(c * 16384);

#pragma unroll
        for (int hf = 0; hf < 2; ++hf) {
            const int krow0 = 64 * hf;
            const unsigned vb0 = vbuf + (unsigned)(hf * 8192);
            const unsigned b00 = vb0;
            const unsigned b01 = vb0 + 512u;
            const unsigned b10 = vb0 + 4096u;
            const unsigned b11 = vb0 + 4608u;

            // ---- QK^T both u, C seeded with -m (pre-centered scores) ----
            const float nm0 = -m_run[0], nm1 = -m_run[1];
            const f32x4 ci0 = {nm0, nm0, nm0, nm0};
            const f32x4 ci1 = {nm1, nm1, nm1, nm1};
            f32x4 s[2][4];
            __builtin_amdgcn_s_setprio(1);
#pragma unroll
            for (int mt = 0; mt < 4; ++mt) {
                const int row = (krow0 + l15 + 16 * mt) * KP;
                const f16x8 k0 = *(const f16x8*)&Kt[c][row + 8 * g];
                const f16x8 k1 = *(const f16x8*)&Kt[c][row + 32 + 8 * g];
                s[0][mt] = __builtin_amdgcn_mfma_f32_16x16x32_f16(k0, qf[0][0], ci0, 0, 0, 0);
                s[0][mt] = __builtin_amdgcn_mfma_f32_16x16x32_f16(k1, qf[0][1], s[0][mt], 0, 0, 0);
                s[1][mt] = __builtin_amdgcn_mfma_f32_16x16x32_f16(k0, qf[1][0], ci1, 0, 0, 0);
                s[1][mt] = __builtin_amdgcn_mfma_f32_16x16x32_f16(k1, qf[1][1], s[1][mt], 0, 0, 0);
            }
            __builtin_amdgcn_s_setprio(0);

            // T14-lite: after the LAST K-fragment read of this tile, issue
            // next tile's K loads; they ride under softmax + PV of hf=1.
            if (hf == 1 && t + 1 < NTILE) {
                kp0 = *(const float4*)(kpre + offA);
                kp1 = *(const float4*)(kpre + offB);
                kp2 = *(const float4*)(kpre + offC);
                kp3 = *(const float4*)(kpre + offD);
            }

            // ---- softmax both u -> packed P words ----
            unsigned W[2][4][2];
#pragma unroll
            for (int u = 0; u < 2; ++u) {
                // s is already centered on m_run; tmax is the EXCESS over m_run
                float m0 = fmaxf(fmaxf(s[u][0][0], s[u][0][1]), s[u][0][2]);
                float m1 = fmaxf(fmaxf(s[u][0][3], s[u][1][0]), s[u][1][1]);
                float m2 = fmaxf(fmaxf(s[u][1][2], s[u][1][3]), s[u][2][0]);
                float m3 = fmaxf(fmaxf(s[u][2][1], s[u][2][2]), s[u][2][3]);
                float m4 = fmaxf(fmaxf(s[u][3][0], s[u][3][1]), s[u][3][2]);
                float tmax = fmaxf(fmaxf(m0, m1), fmaxf(fmaxf(m2, m3), fmaxf(m4, s[u][3][3])));
                tmax = gmax4(tmax);   // permlane-based cross-group reduce

                // T13 defer-max: fire only if excess > THR (rare)
                if (!__all(tmax <= DEFER_THR)) {
                    const float dd  = fmaxf(tmax, 0.f);       // per-row shift
                    const float fac = EXP2R(-dd);
                    l_run[u] *= fac;
                    m_run[u] += dd;
#pragma unroll
                    for (int r = 0; r < 4; ++r) {
                        const float fr = __shfl(fac, 4 * g + r);
#pragma unroll
                        for (int nt = 0; nt < 4; ++nt) acc[u][nt][r] *= fr;
                    }
#pragma unroll
                    for (int mt = 0; mt < 4; ++mt)
#pragma unroll
                        for (int r = 0; r < 4; ++r) s[u][mt][r] -= dd;
                }

                float psum = 0.f;
#pragma unroll
                for (int mt = 0; mt < 4; ++mt) {
                    float p0 = EXP2R(s[u][mt][0]);
                    float p1 = EXP2R(s[u][mt][1]);
                    float p2 = EXP2R(s[u][mt][2]);
                    float p3 = EXP2R(s[u][mt][3]);
                    union { fp16x2 f2; unsigned wq; } u0, u1;
                    u0.f2 = __builtin_amdgcn_cvt_pkrtz(p0, p1);
                    u1.f2 = __builtin_amdgcn_cvt_pkrtz(p2, p3);
#if defined(__has_builtin) && __has_builtin(__builtin_amdgcn_fdot2)
                    psum = __builtin_amdgcn_fdot2(u0.f2, ones2, psum, false);
                    psum = __builtin_amdgcn_fdot2(u1.f2, ones2, psum, false);
#else
                    psum += (p0 + p1) + (p2 + p3);
#endif
                    W[u][mt][0] = u0.wq;
                    W[u][mt][1] = u1.wq;
                }
                l_run[u] += psum;   // per-lane partial
            }

            // ---- PV: one tr-read set per ks, shared by both u ----
#pragma unroll
            for (int ks = 0; ks < 2; ++ks) {
                TrP tp[4];
                const unsigned bh0 = ks ? b10 : b00;
                const unsigned bh1 = ks ? b11 : b01;
                TRRD(tp[0].h[0], bh0, "0");   TRRD(tp[0].h[1], bh1, "0");
                TRRD(tp[1].h[0], bh0, "128"); TRRD(tp[1].h[1], bh1, "128");
                TRRD(tp[2].h[0], bh0, "256"); TRRD(tp[2].h[1], bh1, "256");
                TRRD(tp[3].h[0], bh0, "384"); TRRD(tp[3].h[1], bh1, "384");
                asm volatile("s_waitcnt lgkmcnt(0)" ::: "memory");
                __builtin_amdgcn_sched_barrier(0);

#pragma unroll
                for (int u = 0; u < 2; ++u) {
                    unsigned Ta[4];
#pragma unroll
                    for (int h = 0; h < 2; ++h) {
                        u32x2 r1 = __builtin_amdgcn_permlane32_swap(W[u][2 * ks][h], W[u][2 * ks + 1][h], false, false);
                        u32x2 r2 = __builtin_amdgcn_permlane16_swap(r1[0], r1[1], false, false);
                        Ta[h]     = r2[0];
                        Ta[2 + h] = r2[1];
                    }
                    union { unsigned w2[4]; f16x8 v; } pau;
                    pau.w2[0] = Ta[0]; pau.w2[1] = Ta[1];
                    pau.w2[2] = Ta[2]; pau.w2[3] = Ta[3];

                    __builtin_amdgcn_s_setprio(1);
#pragma unroll
                    for (int nt = 0; nt < 4; ++nt)
                        acc[u][nt] = __builtin_amdgcn_mfma_f32_16x16x32_f16(pau.v, tp[nt].v8, acc[u][nt], 0, 0, 0);
                    __builtin_amdgcn_s_setprio(0);
                }
            }
        }

        // stage tile t+1: K from the in-flight prefetch, V loaded here
        if (t + 1 < NTILE) {
            f16x4 h;
            CVT4(h, kp0); *(f16x4*)&Kt[c ^ 1][kta] = h;
            CVT4(h, kp1); *(f16x4*)&Kt[c ^ 1][ktb] = h;
            CVT4(h, kp2); *(f16x4*)&Kt[c ^ 1][ktc] = h;
            CVT4(h, kp3); *(f16x4*)&Kt[c ^ 1][ktd] = h;
            float4 v0 = *(const float4*)(vpre + offA);
            float4 v1 = *(const float4*)(vpre + offB);
            float4 v2 = *(const float4*)(vpre + offC);
            float4 v3 = *(const float4*)(vpre + offD);
            CVT4(h, v0); *(f16x4*)&Vt[c ^ 1][vta] = h;
            CVT4(h, v1); *(f16x4*)&Vt[c ^ 1][vtb] = h;
            CVT4(h, v2); *(f16x4*)&Vt[c ^ 1][vtc] = h;
            CVT4(h, v3); *(f16x4*)&Vt[c ^ 1][vtd] = h;
            kpre += KVBLK * DH;
            vpre += KVBLK * DH;
            __syncthreads();
        }
    }

    // epilogue: reduce l partials across the 4 groups, then O = acc / l
#pragma unroll
    for (int u = 0; u < 2; ++u) {
        l_run[u] = gsum4(l_run[u]);
#pragma unroll
        for (int r = 0; r < 4; ++r) {
            const float lr  = __shfl(l_run[u], 4 * g + r);
            const float inv = 1.0f / lr;
            const int row = qb0 + wv * 32 + u * 16 + 4 * g + r;
            float* op = Og + base + (size_t)row * DH;
#pragma unroll
            for (int nt = 0; nt < 4; ++nt)
                op[16 * nt + l15] = acc[u][nt][r] * inv;
        }
    }
}

extern "C" void kernel_launch(void* const* d_in, const int* in_sizes, int n_in,
                              void* d_out, int out_size, void* d_ws, size_t ws_size,
                              hipStream_t stream) {
    const float* Q = (const float*)d_in[0];
    const float* K = (const float*)d_in[1];
    const float* V = (const float*)d_in[2];
    float* O = (float*)d_out;
    fa_fwd<<<dim3(512, 1, 1), dim3(512, 1, 1), 0, stream>>>(Q, K, V, O);
}

// Round 16
// 96.649 us; speedup vs baseline: 1.1649x; 1.1649x over previous
//
#include <hip/hip_runtime.h>

#define NSEQ 2048
#define DH 64
// SCALE * log2(e): softmax tracked in log2 domain (exp -> bare v_exp_f32)
#define QSCALE (0.125f * 1.44269504088896340736f)
#define DEFER_THR 11.5415603f   // 8 * log2(e)
#define QBLK 256
#define KVBLK 128
#define NTILE (NSEQ / KVBLK)    // 16
#define KP 72   // Kt row pitch (144B): conflict-minimal b128 reads, 2-way writes

typedef _Float16 f16x8 __attribute__((ext_vector_type(8)));
typedef _Float16 f16x4 __attribute__((ext_vector_type(4)));
typedef __fp16 fp16x2 __attribute__((ext_vector_type(2)));
typedef float f32x4 __attribute__((ext_vector_type(4)));
typedef unsigned u32x2 __attribute__((ext_vector_type(2)));

// RAW v_exp_f32 (2^x; flush-to-zero for x<-126 is semantically fine here).
#if defined(__has_builtin) && __has_builtin(__builtin_amdgcn_exp2f)
#define EXP2R(x) __builtin_amdgcn_exp2f(x)
#else
static __device__ __forceinline__ float EXP2R(float x) {
    float r; asm("v_exp_f32 %0, %1" : "=v"(r) : "v"(x)); return r;
}
#endif

// Cross-group (lane^32 then lane^16) reduce via permlane swaps: VALU-only,
// replaces ds_bpermute-based __shfl_xor on the softmax critical path.
static __device__ __forceinline__ float gmax4(float x) {
    unsigned xu = __float_as_uint(x);
    u32x2 p = __builtin_amdgcn_permlane32_swap(xu, xu, false, false);
    float y = fmaxf(__uint_as_float(p[0]), __uint_as_float(p[1]));
    unsigned yu = __float_as_uint(y);
    u32x2 q = __builtin_amdgcn_permlane16_swap(yu, yu, false, false);
    return fmaxf(__uint_as_float(q[0]), __uint_as_float(q[1]));
}
static __device__ __forceinline__ float gsum4(float x) {
    unsigned xu = __float_as_uint(x);
    u32x2 p = __builtin_amdgcn_permlane32_swap(xu, xu, false, false);
    float y = __uint_as_float(p[0]) + __uint_as_float(p[1]);
    unsigned yu = __float_as_uint(y);
    u32x2 q = __builtin_amdgcn_permlane16_swap(yu, yu, false, false);
    return __uint_as_float(q[0]) + __uint_as_float(q[1]);
}

union TrP { f16x4 h[2]; f16x8 v8; };

// tr-read: per-lane addr = 128B-aligned subtile base + l15*8
#define TRRD(dst, bb, lit) \
    asm volatile("ds_read_b64_tr_b16 %0, %1 offset:" lit : "=v"(dst) : "v"(bb))

// float4 -> f16x4 via packed cvt
#define CVT4(dst, f4) do { \
        union { fp16x2 f2[2]; f16x4 h4; } _u; \
        _u.f2[0] = __builtin_amdgcn_cvt_pkrtz((f4).x, (f4).y); \
        _u.f2[1] = __builtin_amdgcn_cvt_pkrtz((f4).z, (f4).w); \
        (dst) = _u.h4; } while (0)

__global__ __launch_bounds__(512, 4)
void fa_fwd(const float* __restrict__ Qg, const float* __restrict__ Kg,
            const float* __restrict__ Vg, float* __restrict__ Og)
{
    __shared__ _Float16 Kt[2][KVBLK * KP];   // 36864 B
    __shared__ _Float16 Vt[2][KVBLK * DH];   // 32768 B, subtiled [kv/4][d/16][4][16]

    const int tid  = threadIdx.x;
    const int lane = tid & 63;
    const int wv   = tid >> 6;
    const int l15  = lane & 15;
    const int g    = lane >> 4;

    // XCD-aware swizzle: 512 blocks / 8 XCDs
    const int id  = blockIdx.x;
    const int w   = (id & 7) * 64 + (id >> 3);
    const int bh  = w >> 3;
    const int qb0 = (w & 7) * QBLK;
    const size_t base = (size_t)bh * NSEQ * DH;

    f16x8 qf[2][2];
#pragma unroll
    for (int u = 0; u < 2; ++u) {
        const float* qp = Qg + base + (size_t)(qb0 + wv * 32 + u * 16 + l15) * DH;
#pragma unroll
        for (int ks = 0; ks < 2; ++ks)
#pragma unroll
            for (int j = 0; j < 8; ++j)
                qf[u][ks][j] = (_Float16)(qp[32 * ks + 8 * g + j] * QSCALE);
    }

    f32x4 acc[2][4];
#pragma unroll
    for (int u = 0; u < 2; ++u)
#pragma unroll
        for (int nt = 0; nt < 4; ++nt)
            acc[u][nt] = (f32x4){0.f, 0.f, 0.f, 0.f};
    // m starts at 0 (finite) so -m seeds the MFMA C operand; defer-max
    // handles growth (fires only when excess > THR).
    float m_run[2] = {0.f, 0.f};
    float l_run[2] = {0.f, 0.f};   // per-lane PARTIAL; reduced in epilogue

    // staging map (conflict-free Vt writes), covering 128 kv rows
    const int grp = tid >> 4;
    const int kb4 = grp >> 1;
    const int dhh = (grp & 1) * 32;
    const int kva = kb4 * 4 + (l15 >> 2);
    const int d0a = dhh + (l15 & 3) * 4;
    const int d0b = d0a + 16;
    const float* Kbp = Kg + base;
    const float* Vbp = Vg + base;
    const int offA = kva * DH + d0a;
    const int offB = kva * DH + d0b;
    const int offC = offA + 64 * DH;
    const int offD = offB + 64 * DH;
    const int vta = ((kva >> 2) * 4 + (d0a >> 4)) * 64 + (kva & 3) * 16 + (d0a & 15);
    const int vtb = ((kva >> 2) * 4 + (d0b >> 4)) * 64 + (kva & 3) * 16 + (d0b & 15);
    const int vtc = vta + 4096;
    const int vtd = vtb + 4096;
    const int kta = kva * KP + d0a;
    const int ktb = kva * KP + d0b;
    const int ktc = kta + 64 * KP;
    const int ktd = ktb + 64 * KP;

    // STAGE: load + convert + write in one tight region. Short register
    // lifetimes are MANDATORY: any tile-scale float4 prefetch (rounds 12, 15)
    // blows the 64-arch-VGPR budget and spills ~100 MB to scratch. Latency
    // is covered by the other resident block on the CU.
#define STAGE(bb, kp_, vp_) do { \
        float4 f0 = *(const float4*)((kp_) + offA); \
        float4 f1 = *(const float4*)((kp_) + offB); \
        float4 f2 = *(const float4*)((kp_) + offC); \
        float4 f3 = *(const float4*)((kp_) + offD); \
        float4 f4v = *(const float4*)((vp_) + offA); \
        float4 f5 = *(const float4*)((vp_) + offB); \
        float4 f6 = *(const float4*)((vp_) + offC); \
        float4 f7 = *(const float4*)((vp_) + offD); \
        f16x4 h; \
        CVT4(h, f0); *(f16x4*)&Kt[bb][kta] = h; \
        CVT4(h, f1); *(f16x4*)&Kt[bb][ktb] = h; \
        CVT4(h, f2); *(f16x4*)&Kt[bb][ktc] = h; \
        CVT4(h, f3); *(f16x4*)&Kt[bb][ktd] = h; \
        CVT4(h, f4v); *(f16x4*)&Vt[bb][vta] = h; \
        CVT4(h, f5); *(f16x4*)&Vt[bb][vtb] = h; \
        CVT4(h, f6); *(f16x4*)&Vt[bb][vtc] = h; \
        CVT4(h, f7); *(f16x4*)&Vt[bb][vtd] = h; \
    } while (0)

    STAGE(0, Kbp, Vbp);
    __syncthreads();

    const float* kpre = Kbp + KVBLK * DH;
    const float* vpre = Vbp + KVBLK * DH;

    const unsigned vtrb = (unsigned)(size_t)(&Vt[0][0]) + (unsigned)(g * 1024 + l15 * 8);
    const fp16x2 ones2 = {(__fp16)1.0f, (__fp16)1.0f};

    for (int t = 0; t < NTILE; ++t) {
        const int c = t & 1;
        const unsigned vbuf = vtrb + (unsigned)(c * 16384);

#pragma unroll
        for (int hf = 0; hf < 2; ++hf) {
            const int krow0 = 64 * hf;
            const unsigned vb0 = vbuf + (unsigned)(hf * 8192);
            const unsigned b00 = vb0;
            const unsigned b01 = vb0 + 512u;
            const unsigned b10 = vb0 + 4096u;
            const unsigned b11 = vb0 + 4608u;

            // ---- QK^T both u, C seeded with -m (pre-centered scores) ----
            const float nm0 = -m_run[0], nm1 = -m_run[1];
            const f32x4 ci0 = {nm0, nm0, nm0, nm0};
            const f32x4 ci1 = {nm1, nm1, nm1, nm1};
            f32x4 s[2][4];
            __builtin_amdgcn_s_setprio(1);
#pragma unroll
            for (int mt = 0; mt < 4; ++mt) {
                const int row = (krow0 + l15 + 16 * mt) * KP;
                const f16x8 k0 = *(const f16x8*)&Kt[c][row + 8 * g];
                const f16x8 k1 = *(const f16x8*)&Kt[c][row + 32 + 8 * g];
                s[0][mt] = __builtin_amdgcn_mfma_f32_16x16x32_f16(k0, qf[0][0], ci0, 0, 0, 0);
                s[0][mt] = __builtin_amdgcn_mfma_f32_16x16x32_f16(k1, qf[0][1], s[0][mt], 0, 0, 0);
                s[1][mt] = __builtin_amdgcn_mfma_f32_16x16x32_f16(k0, qf[1][0], ci1, 0, 0, 0);
                s[1][mt] = __builtin_amdgcn_mfma_f32_16x16x32_f16(k1, qf[1][1], s[1][mt], 0, 0, 0);
            }
            __builtin_amdgcn_s_setprio(0);

            // ---- softmax both u -> packed P words ----
            unsigned W[2][4][2];
#pragma unroll
            for (int u = 0; u < 2; ++u) {
                // s is already centered on m_run; tmax is the EXCESS over m_run
                float m0 = fmaxf(fmaxf(s[u][0][0], s[u][0][1]), s[u][0][2]);
                float m1 = fmaxf(fmaxf(s[u][0][3], s[u][1][0]), s[u][1][1]);
                float m2 = fmaxf(fmaxf(s[u][1][2], s[u][1][3]), s[u][2][0]);
                float m3 = fmaxf(fmaxf(s[u][2][1], s[u][2][2]), s[u][2][3]);
                float m4 = fmaxf(fmaxf(s[u][3][0], s[u][3][1]), s[u][3][2]);
                float tmax = fmaxf(fmaxf(m0, m1), fmaxf(fmaxf(m2, m3), fmaxf(m4, s[u][3][3])));
                tmax = gmax4(tmax);   // permlane-based cross-group reduce

                // T13 defer-max: fire only if excess > THR (rare)
                if (!__all(tmax <= DEFER_THR)) {
                    const float dd  = fmaxf(tmax, 0.f);       // per-row shift
                    const float fac = EXP2R(-dd);
                    l_run[u] *= fac;
                    m_run[u] += dd;
#pragma unroll
                    for (int r = 0; r < 4; ++r) {
                        const float fr = __shfl(fac, 4 * g + r);
#pragma unroll
                        for (int nt = 0; nt < 4; ++nt) acc[u][nt][r] *= fr;
                    }
#pragma unroll
                    for (int mt = 0; mt < 4; ++mt)
#pragma unroll
                        for (int r = 0; r < 4; ++r) s[u][mt][r] -= dd;
                }

                float psum = 0.f;
#pragma unroll
                for (int mt = 0; mt < 4; ++mt) {
                    float p0 = EXP2R(s[u][mt][0]);
                    float p1 = EXP2R(s[u][mt][1]);
                    float p2 = EXP2R(s[u][mt][2]);
                    float p3 = EXP2R(s[u][mt][3]);
                    union { fp16x2 f2; unsigned wq; } u0, u1;
                    u0.f2 = __builtin_amdgcn_cvt_pkrtz(p0, p1);
                    u1.f2 = __builtin_amdgcn_cvt_pkrtz(p2, p3);
#if defined(__has_builtin) && __has_builtin(__builtin_amdgcn_fdot2)
                    psum = __builtin_amdgcn_fdot2(u0.f2, ones2, psum, false);
                    psum = __builtin_amdgcn_fdot2(u1.f2, ones2, psum, false);
#else
                    psum += (p0 + p1) + (p2 + p3);
#endif
                    W[u][mt][0] = u0.wq;
                    W[u][mt][1] = u1.wq;
                }
                l_run[u] += psum;   // per-lane partial
            }

            // ---- PV: one tr-read set per ks, shared by both u ----
#pragma unroll
            for (int ks = 0; ks < 2; ++ks) {
                TrP tp[4];
                const unsigned bh0 = ks ? b10 : b00;
                const unsigned bh1 = ks ? b11 : b01;
                TRRD(tp[0].h[0], bh0, "0");   TRRD(tp[0].h[1], bh1, "0");
                TRRD(tp[1].h[0], bh0, "128"); TRRD(tp[1].h[1], bh1, "128");
                TRRD(tp[2].h[0], bh0, "256"); TRRD(tp[2].h[1], bh1, "256");
                TRRD(tp[3].h[0], bh0, "384"); TRRD(tp[3].h[1], bh1, "384");
                asm volatile("s_waitcnt lgkmcnt(0)" ::: "memory");
                __builtin_amdgcn_sched_barrier(0);

#pragma unroll
                for (int u = 0; u < 2; ++u) {
                    unsigned Ta[4];
#pragma unroll
                    for (int h = 0; h < 2; ++h) {
                        u32x2 r1 = __builtin_amdgcn_permlane32_swap(W[u][2 * ks][h], W[u][2 * ks + 1][h], false, false);
                        u32x2 r2 = __builtin_amdgcn_permlane16_swap(r1[0], r1[1], false, false);
                        Ta[h]     = r2[0];
                        Ta[2 + h] = r2[1];
                    }
                    union { unsigned w2[4]; f16x8 v; } pau;
                    pau.w2[0] = Ta[0]; pau.w2[1] = Ta[1];
                    pau.w2[2] = Ta[2]; pau.w2[3] = Ta[3];

                    __builtin_amdgcn_s_setprio(1);
#pragma unroll
                    for (int nt = 0; nt < 4; ++nt)
                        acc[u][nt] = __builtin_amdgcn_mfma_f32_16x16x32_f16(pau.v, tp[nt].v8, acc[u][nt], 0, 0, 0);
                    __builtin_amdgcn_s_setprio(0);
                }
            }
        }

        // stage tile t+1 (load+cvt+write, short-lived regs), single barrier
        if (t + 1 < NTILE) {
            STAGE(c ^ 1, kpre, vpre);
            kpre += KVBLK * DH;
            vpre += KVBLK * DH;
            __syncthreads();
        }
    }

    // epilogue: reduce l partials across the 4 groups, then O = acc / l
#pragma unroll
    for (int u = 0; u < 2; ++u) {
        l_run[u] = gsum4(l_run[u]);
#pragma unroll
        for (int r = 0; r < 4; ++r) {
            const float lr  = __shfl(l_run[u], 4 * g + r);
            const float inv = 1.0f / lr;
            const int row = qb0 + wv * 32 + u * 16 + 4 * g + r;
            float* op = Og + base + (size_t)row * DH;
#pragma unroll
            for (int nt = 0; nt < 4; ++nt)
                op[16 * nt + l15] = acc[u][nt][r] * inv;
        }
    }
}

extern "C" void kernel_launch(void* const* d_in, const int* in_sizes, int n_in,
                              void* d_out, int out_size, void* d_ws, size_t ws_size,
                              hipStream_t stream) {
    const float* Q = (const float*)d_in[0];
    const float* K = (const float*)d_in[1];
    const float* V = (const float*)d_in[2];
    float* O = (float*)d_out;
    fa_fwd<<<dim3(512, 1, 1), dim3(512, 1, 1), 0, stream>>>(Q, K, V, O);
}

// Round 18
// 96.100 us; speedup vs baseline: 1.1716x; 1.0057x over previous
//
#include <hip/hip_runtime.h>

#define NSEQ 2048
#define DH 64
// SCALE * log2(e): softmax tracked in log2 domain (exp -> bare v_exp_f32)
#define QSCALE (0.125f * 1.44269504088896340736f)
#define DEFER_THR 11.5415603f   // 8 * log2(e)
#define QBLK 256
#define KVBLK 128
#define NTILE (NSEQ / KVBLK)    // 16
#define KP 72   // Kt row pitch (144B): conflict-minimal b128 reads, 2-way writes

typedef _Float16 f16x8 __attribute__((ext_vector_type(8)));
typedef _Float16 f16x4 __attribute__((ext_vector_type(4)));
typedef __fp16 fp16x2 __attribute__((ext_vector_type(2)));
typedef float f32x4 __attribute__((ext_vector_type(4)));
typedef unsigned u32x2 __attribute__((ext_vector_type(2)));

// RAW v_exp_f32 (2^x; flush-to-zero for x<-126 is semantically fine here).
#if defined(__has_builtin) && __has_builtin(__builtin_amdgcn_exp2f)
#define EXP2R(x) __builtin_amdgcn_exp2f(x)
#else
static __device__ __forceinline__ float EXP2R(float x) {
    float r; asm("v_exp_f32 %0, %1" : "=v"(r) : "v"(x)); return r;
}
#endif

// Cross-group (lane^32 then lane^16) reduce via permlane swaps: VALU-only.
static __device__ __forceinline__ float gmax4(float x) {
    unsigned xu = __float_as_uint(x);
    u32x2 p = __builtin_amdgcn_permlane32_swap(xu, xu, false, false);
    float y = fmaxf(__uint_as_float(p[0]), __uint_as_float(p[1]));
    unsigned yu = __float_as_uint(y);
    u32x2 q = __builtin_amdgcn_permlane16_swap(yu, yu, false, false);
    return fmaxf(__uint_as_float(q[0]), __uint_as_float(q[1]));
}
static __device__ __forceinline__ float gsum4(float x) {
    unsigned xu = __float_as_uint(x);
    u32x2 p = __builtin_amdgcn_permlane32_swap(xu, xu, false, false);
    float y = __uint_as_float(p[0]) + __uint_as_float(p[1]);
    unsigned yu = __float_as_uint(y);
    u32x2 q = __builtin_amdgcn_permlane16_swap(yu, yu, false, false);
    return __uint_as_float(q[0]) + __uint_as_float(q[1]);
}

union TrP { f16x4 h[2]; f16x8 v8; };

// tr-read: per-lane addr = subtile-region + lane offsets; the wave reads
// ONE CONTIGUOUS 512B region per TRRD (4 groups at g*128) -- the m156
// canonical pattern, eliminating the 4-way same-bank conflict of the old
// g*1024-strided placement.
#define TRRD(dst, bb, lit) \
    asm volatile("ds_read_b64_tr_b16 %0, %1 offset:" lit : "=v"(dst) : "v"(bb))

// float4 -> f16x4 via packed cvt
#define CVT4(dst, f4) do { \
        union { fp16x2 f2[2]; f16x4 h4; } _u; \
        _u.f2[0] = __builtin_amdgcn_cvt_pkrtz((f4).x, (f4).y); \
        _u.f2[1] = __builtin_amdgcn_cvt_pkrtz((f4).z, (f4).w); \
        (dst) = _u.h4; } while (0)

__global__ __launch_bounds__(512, 4)
void fa_fwd(const float* __restrict__ Qg, const float* __restrict__ Kg,
            const float* __restrict__ Vg, float* __restrict__ Og)
{
    __shared__ _Float16 Kt[2][KVBLK * KP];   // 36864 B
    // Vt placement (per 64-kv half, 8192 B): subtile (kv4, nt) with
    // kv4 = 8ks+2g+h2 lives at byte (((ks*2+h2)*4+nt)*4+g)*128, internal
    // 4x16 f16 row-major (r*32 + cc*2). Simultaneously-read subtiles
    // (fixed ks,h2,nt; g=0..3) are CONSECUTIVE 128B blocks.
    __shared__ _Float16 Vt[2][KVBLK * DH];   // 32768 B

    const int tid  = threadIdx.x;
    const int lane = tid & 63;
    const int wv   = tid >> 6;
    const int l15  = lane & 15;
    const int g    = lane >> 4;

    // XCD-aware swizzle: 512 blocks / 8 XCDs
    const int id  = blockIdx.x;
    const int w   = (id & 7) * 64 + (id >> 3);
    const int bh  = w >> 3;
    const int qb0 = (w & 7) * QBLK;
    const size_t base = (size_t)bh * NSEQ * DH;

    f16x8 qf[2][2];
#pragma unroll
    for (int u = 0; u < 2; ++u) {
        const float* qp = Qg + base + (size_t)(qb0 + wv * 32 + u * 16 + l15) * DH;
#pragma unroll
        for (int ks = 0; ks < 2; ++ks)
#pragma unroll
            for (int j = 0; j < 8; ++j)
                qf[u][ks][j] = (_Float16)(qp[32 * ks + 8 * g + j] * QSCALE);
    }

    f32x4 acc[2][4];
#pragma unroll
    for (int u = 0; u < 2; ++u)
#pragma unroll
        for (int nt = 0; nt < 4; ++nt)
            acc[u][nt] = (f32x4){0.f, 0.f, 0.f, 0.f};
    // m starts at 0 (finite) so -m seeds the MFMA C operand; defer-max
    // handles growth (fires only when excess > THR).
    float m_run[2] = {0.f, 0.f};
    float l_run[2] = {0.f, 0.f};   // per-lane PARTIAL; reduced in epilogue

    // staging map, covering 128 kv rows
    const int grp = tid >> 4;
    const int kb4 = grp >> 1;            // kv4 of this group's rows
    const int dhh = (grp & 1) * 32;
    const int kva = kb4 * 4 + (l15 >> 2);
    const int d0a = dhh + (l15 & 3) * 4;
    const int d0b = d0a + 16;
    const float* Kbp = Kg + base;
    const float* Vbp = Vg + base;
    const int offA = kva * DH + d0a;
    const int offB = kva * DH + d0b;
    const int offC = offA + 64 * DH;
    const int offD = offB + 64 * DH;
    // Vt slots (f16 elements) under the new placement
    const int ks_a = kb4 >> 3;
    const int h2_a = kb4 & 1;
    const int g_a  = (kb4 >> 1) & 3;
    const int ntA  = d0a >> 4;           // 0 or 2
    const int inr  = (l15 >> 2) * 16 + (l15 & 3) * 4;   // r*16 + cc (elements)
    const int vta = (((ks_a * 2 + h2_a) * 4 + ntA) * 4 + g_a) * 64 + inr;
    const int vtb = (((ks_a * 2 + h2_a) * 4 + ntA + 1) * 4 + g_a) * 64 + inr;
    const int vtc = vta + 4096;          // second 64-kv half
    const int vtd = vtb + 4096;
    const int kta = kva * KP + d0a;
    const int ktb = kva * KP + d0b;
    const int ktc = kta + 64 * KP;
    const int ktd = ktb + 64 * KP;

    // STAGE: load + convert + write in one tight region. Short register
    // lifetimes are MANDATORY (rounds 12/15: tile-scale prefetch spills).
#define STAGE(bb, kp_, vp_) do { \
        float4 f0 = *(const float4*)((kp_) + offA); \
        float4 f1 = *(const float4*)((kp_) + offB); \
        float4 f2 = *(const float4*)((kp_) + offC); \
        float4 f3 = *(const float4*)((kp_) + offD); \
        float4 f4v = *(const float4*)((vp_) + offA); \
        float4 f5 = *(const float4*)((vp_) + offB); \
        float4 f6 = *(const float4*)((vp_) + offC); \
        float4 f7 = *(const float4*)((vp_) + offD); \
        f16x4 h; \
        CVT4(h, f0); *(f16x4*)&Kt[bb][kta] = h; \
        CVT4(h, f1); *(f16x4*)&Kt[bb][ktb] = h; \
        CVT4(h, f2); *(f16x4*)&Kt[bb][ktc] = h; \
        CVT4(h, f3); *(f16x4*)&Kt[bb][ktd] = h; \
        CVT4(h, f4v); *(f16x4*)&Vt[bb][vta] = h; \
        CVT4(h, f5); *(f16x4*)&Vt[bb][vtb] = h; \
        CVT4(h, f6); *(f16x4*)&Vt[bb][vtc] = h; \
        CVT4(h, f7); *(f16x4*)&Vt[bb][vtd] = h; \
    } while (0)

    STAGE(0, Kbp, Vbp);
    __syncthreads();

    const float* kpre = Kbp + KVBLK * DH;
    const float* vpre = Vbp + KVBLK * DH;

    // per-lane tr base: group g's subtile column, contiguous across the wave
    const unsigned vtrb = (unsigned)(size_t)(&Vt[0][0]) + (unsigned)(g * 128 + l15 * 8);
    const fp16x2 ones2 = {(__fp16)1.0f, (__fp16)1.0f};

    for (int t = 0; t < NTILE; ++t) {
        const int c = t & 1;
        const unsigned vbuf = vtrb + (unsigned)(c * 16384);

#pragma unroll
        for (int hf = 0; hf < 2; ++hf) {
            const int krow0 = 64 * hf;
            const unsigned vb0 = vbuf + (unsigned)(hf * 8192);
            const unsigned b00 = vb0;            // ks=0, h2=0
            const unsigned b01 = vb0 + 2048u;    // ks=0, h2=1
            const unsigned b10 = vb0 + 4096u;    // ks=1, h2=0
            const unsigned b11 = vb0 + 6144u;    // ks=1, h2=1

            // ---- QK^T both u, C seeded with -m (pre-centered scores) ----
            const float nm0 = -m_run[0], nm1 = -m_run[1];
            const f32x4 ci0 = {nm0, nm0, nm0, nm0};
            const f32x4 ci1 = {nm1, nm1, nm1, nm1};
            f32x4 s[2][4];
            __builtin_amdgcn_s_setprio(1);
#pragma unroll
            for (int mt = 0; mt < 4; ++mt) {
                const int row = (krow0 + l15 + 16 * mt) * KP;
                const f16x8 k0 = *(const f16x8*)&Kt[c][row + 8 * g];
                const f16x8 k1 = *(const f16x8*)&Kt[c][row + 32 + 8 * g];
                s[0][mt] = __builtin_amdgcn_mfma_f32_16x16x32_f16(k0, qf[0][0], ci0, 0, 0, 0);
                s[0][mt] = __builtin_amdgcn_mfma_f32_16x16x32_f16(k1, qf[0][1], s[0][mt], 0, 0, 0);
                s[1][mt] = __builtin_amdgcn_mfma_f32_16x16x32_f16(k0, qf[1][0], ci1, 0, 0, 0);
                s[1][mt] = __builtin_amdgcn_mfma_f32_16x16x32_f16(k1, qf[1][1], s[1][mt], 0, 0, 0);
            }
            __builtin_amdgcn_s_setprio(0);

            // ---- softmax both u -> packed P words ----
            unsigned W[2][4][2];
#pragma unroll
            for (int u = 0; u < 2; ++u) {
                // s is already centered on m_run; tmax is the EXCESS over m_run
                float m0 = fmaxf(fmaxf(s[u][0][0], s[u][0][1]), s[u][0][2]);
                float m1 = fmaxf(fmaxf(s[u][0][3], s[u][1][0]), s[u][1][1]);
                float m2 = fmaxf(fmaxf(s[u][1][2], s[u][1][3]), s[u][2][0]);
                float m3 = fmaxf(fmaxf(s[u][2][1], s[u][2][2]), s[u][2][3]);
                float m4 = fmaxf(fmaxf(s[u][3][0], s[u][3][1]), s[u][3][2]);
                float tmax = fmaxf(fmaxf(m0, m1), fmaxf(fmaxf(m2, m3), fmaxf(m4, s[u][3][3])));
                tmax = gmax4(tmax);

                // T13 defer-max: fire only if excess > THR (rare)
                if (!__all(tmax <= DEFER_THR)) {
                    const float dd  = fmaxf(tmax, 0.f);       // per-row shift
                    const float fac = EXP2R(-dd);
                    l_run[u] *= fac;
                    m_run[u] += dd;
#pragma unroll
                    for (int r = 0; r < 4; ++r) {
                        const float fr = __shfl(fac, 4 * g + r);
#pragma unroll
                        for (int nt = 0; nt < 4; ++nt) acc[u][nt][r] *= fr;
                    }
#pragma unroll
                    for (int mt = 0; mt < 4; ++mt)
#pragma unroll
                        for (int r = 0; r < 4; ++r) s[u][mt][r] -= dd;
                }

                float psum = 0.f;
#pragma unroll
                for (int mt = 0; mt < 4; ++mt) {
                    float p0 = EXP2R(s[u][mt][0]);
                    float p1 = EXP2R(s[u][mt][1]);
                    float p2 = EXP2R(s[u][mt][2]);
                    float p3 = EXP2R(s[u][mt][3]);
                    union { fp16x2 f2; unsigned wq; } u0, u1;
                    u0.f2 = __builtin_amdgcn_cvt_pkrtz(p0, p1);
                    u1.f2 = __builtin_amdgcn_cvt_pkrtz(p2, p3);
#if defined(__has_builtin) && __has_builtin(__builtin_amdgcn_fdot2)
                    psum = __builtin_amdgcn_fdot2(u0.f2, ones2, psum, false);
                    psum = __builtin_amdgcn_fdot2(u1.f2, ones2, psum, false);
#else
                    psum += (p0 + p1) + (p2 + p3);
#endif
                    W[u][mt][0] = u0.wq;
                    W[u][mt][1] = u1.wq;
                }
                l_run[u] += psum;   // per-lane partial
            }

            // ---- PV: one tr-read set per ks, shared by both u ----
#pragma unroll
            for (int ks = 0; ks < 2; ++ks) {
                TrP tp[4];
                const unsigned bh0 = ks ? b10 : b00;
                const unsigned bh1 = ks ? b11 : b01;
                TRRD(tp[0].h[0], bh0, "0");    TRRD(tp[0].h[1], bh1, "0");
                TRRD(tp[1].h[0], bh0, "512");  TRRD(tp[1].h[1], bh1, "512");
                TRRD(tp[2].h[0], bh0, "1024"); TRRD(tp[2].h[1], bh1, "1024");
                TRRD(tp[3].h[0], bh0, "1536"); TRRD(tp[3].h[1], bh1, "1536");
                asm volatile("s_waitcnt lgkmcnt(0)" ::: "memory");
                __builtin_amdgcn_sched_barrier(0);

#pragma unroll
                for (int u = 0; u < 2; ++u) {
                    unsigned Ta[4];
#pragma unroll
                    for (int h = 0; h < 2; ++h) {
                        u32x2 r1 = __builtin_amdgcn_permlane32_swap(W[u][2 * ks][h], W[u][2 * ks + 1][h], false, false);
                        u32x2 r2 = __builtin_amdgcn_permlane16_swap(r1[0], r1[1], false, false);
                        Ta[h]     = r2[0];
                        Ta[2 + h] = r2[1];
                    }
                    union { unsigned w2[4]; f16x8 v; } pau;
                    pau.w2[0] = Ta[0]; pau.w2[1] = Ta[1];
                    pau.w2[2] = Ta[2]; pau.w2[3] = Ta[3];

                    __builtin_amdgcn_s_setprio(1);
#pragma unroll
                    for (int nt = 0; nt < 4; ++nt)
                        acc[u][nt] = __builtin_amdgcn_mfma_f32_16x16x32_f16(pau.v, tp[nt].v8, acc[u][nt], 0, 0, 0);
                    __builtin_amdgcn_s_setprio(0);
                }
            }
        }

        // stage tile t+1 (load+cvt+write, short-lived regs), single barrier
        if (t + 1 < NTILE) {
            STAGE(c ^ 1, kpre, vpre);
            kpre += KVBLK * DH;
            vpre += KVBLK * DH;
            __syncthreads();
        }
    }

    // epilogue: reduce l partials across the 4 groups, then O = acc / l
#pragma unroll
    for (int u = 0; u < 2; ++u) {
        l_run[u] = gsum4(l_run[u]);
#pragma unroll
        for (int r = 0; r < 4; ++r) {
            const float lr  = __shfl(l_run[u], 4 * g + r);
            const float inv = 1.0f / lr;
            const int row = qb0 + wv * 32 + u * 16 + 4 * g + r;
            float* op = Og + base + (size_t)row * DH;
#pragma unroll
            for (int nt = 0; nt < 4; ++nt)
                op[16 * nt + l15] = acc[u][nt][r] * inv;
        }
    }
}

extern "C" void kernel_launch(void* const* d_in, const int* in_sizes, int n_in,
                              void* d_out, int out_size, void* d_ws, size_t ws_size,
                              hipStream_t stream) {
    const float* Q = (const float*)d_in[0];
    const float* K = (const float*)d_in[1];
    const float* V = (const float*)d_in[2];
    float* O = (float*)d_out;
    fa_fwd<<<dim3(512, 1, 1), dim3(512, 1, 1), 0, stream>>>(Q, K, V, O);
}